// Round 14
// baseline (320.845 us; speedup 1.0000x reference)
//
#include <hip/hip_runtime.h>

// Problem constants (B=2, C=32, T=8, H=32, W=32, V=8192)
#define NQ    16384      // B*T*H*W
#define CDIM  32
#define VSZ   8192
#define PLANE 8192       // T*H*W
#define BSTR  262144     // C*PLANE
#define NEL   524288     // B*C*T*H*W
#define MARGIN 0.010f    // certainty margin (covers bf16x3 error ~1e-3 with 10x slack)
#define NSEG  32         // V-segments for argmin
#define GUARD 1088       // FH2 row guard (> max |tap shift| = 1057)

typedef unsigned long long u64;
typedef unsigned int u32;
typedef unsigned short u16;
using f32x4 = __attribute__((ext_vector_type(4))) float;
using s16x8 = __attribute__((ext_vector_type(8))) short;

__device__ __forceinline__ u32 flip_bits(u32 b) {
    return (b & 0x80000000u) ? ~b : (b | 0x80000000u);
}
__device__ __forceinline__ float unflip_val(u32 b) {
    u32 u = (b & 0x80000000u) ? (b ^ 0x80000000u) : ~b;
    return __uint_as_float(u);
}
__device__ __forceinline__ u16 bf16_rne(float x) {
    u32 u = __float_as_uint(x);
    return (u16)((u + 0x7fffu + ((u >> 16) & 1u)) >> 16);
}

// ---------------- K1: prep — bf16 hi/lo frags (EF/QF/WF) + enorm + zeros ----------------
// Frag layout (proven R1/R2): lane l holds A/B[row|col = l&15][k = (l>>4)*8 + i].
// WF packs Wmat[col = u*32+co][k = ci] = cw[co*864 + ci*27 + u], 54 col-tiles.
__global__ void k_prep(const float* __restrict__ f, const float* __restrict__ emb,
                       const float* __restrict__ cw,
                       u16* __restrict__ EFh, u16* __restrict__ EFl,
                       u16* __restrict__ QFh, u16* __restrict__ QFl,
                       u16* __restrict__ WFh, u16* __restrict__ WFl,
                       float* __restrict__ enorm, int* __restrict__ counts) {
    int t = blockIdx.x * 256 + threadIdx.x;   // 430*256 = 110080, used 109952
    if (t < 32768) {                          // EF: 512 code tiles x 64 lanes
        int tile = t >> 6, l = t & 63;
        int row = tile * 16 + (l & 15);
        int k0 = (l >> 4) * 8;
        const float* src = emb + row * CDIM + k0;
        s16x8 vh, vl;
#pragma unroll
        for (int i = 0; i < 8; ++i) {
            float v = src[i];
            u16 hb = bf16_rne(v);
            float hf = __uint_as_float(((u32)hb) << 16);
            vh[i] = (short)hb;
            vl[i] = (short)bf16_rne(v - hf);
        }
        *(s16x8*)(EFh + t * 8) = vh;
        *(s16x8*)(EFl + t * 8) = vl;
    } else if (t < 98304) {                   // QF: 1024 query subtiles, q' = -2q
        int t2 = t - 32768;
        int st = t2 >> 6, l = t2 & 63;
        int n = st * 16 + (l & 15);
        int k0 = (l >> 4) * 8;
        int b = n >> 13, p = n & (PLANE - 1);
        const float* fq = f + b * BSTR + p;
        s16x8 vh, vl;
#pragma unroll
        for (int i = 0; i < 8; ++i) {
            float v = -2.0f * fq[(k0 + i) * PLANE];
            u16 hb = bf16_rne(v);
            float hf = __uint_as_float(((u32)hb) << 16);
            vh[i] = (short)hb;
            vl[i] = (short)bf16_rne(v - hf);
        }
        *(s16x8*)(QFh + t2 * 8) = vh;
        *(s16x8*)(QFl + t2 * 8) = vl;
    } else if (t < 106496) {                  // enorm + zero counts
        int j = t - 98304;
        const float4* row = (const float4*)(emb + j * CDIM);
        float s = 0.f;
#pragma unroll
        for (int r = 0; r < 8; ++r) {
            float4 v = row[r];
            s += v.x * v.x + v.y * v.y + v.z * v.z + v.w * v.w;
        }
        enorm[j] = s;
        counts[j] = 0;
    } else if (t < 109952) {                  // WF: 54 col-tiles x 64 lanes
        int i = t - 106496;
        int nt = i >> 6, l = i & 63;
        int col = nt * 16 + (l & 15);         // < 864
        int co = col & 31, u = col >> 5;
        int k0 = (l >> 4) * 8;
        s16x8 vh, vl;
#pragma unroll
        for (int j = 0; j < 8; ++j) {
            int ci = k0 + j;
            float v = cw[co * 864 + ci * 27 + u];
            u16 hb = bf16_rne(v);
            float hf = __uint_as_float(((u32)hb) << 16);
            vh[j] = (short)hb;
            vl[j] = (short)bf16_rne(v - hf);
        }
        *(s16x8*)(WFh + i * 8) = vh;
        *(s16x8*)(WFl + i * 8) = vl;
    }
}

// ---------------- K2: single-pass exact MFMA argmin (QT=4, 1-wave blocks, 32 segs) ----
// grid 8192 x 64. EMPIRICAL OPTIMUM at ~44.6us across seven variants
// (R1/R2/R4/R6/R7/R12/R13): issue-bound (VALUBusy 66% + MfmaUtil 22%) on the
// 5-op exact (m1,m2,idx) tracking. BYTE-IDENTICAL to R13. No cross-block
// fences (R10: 6x slowdown from per-block device-scope L2 writebacks).
__global__ __launch_bounds__(64) void k_mfma3(
    const u16* __restrict__ QFh, const u16* __restrict__ QFl,
    const u16* __restrict__ EFh, const u16* __restrict__ EFl,
    const float* __restrict__ enorm,
    u64* __restrict__ PARTK, float* __restrict__ PARTM2) {
    const int l = threadIdx.x;
    const int lq = (l >> 4) * 4;   // D rows lq..lq+3 (codes), col = l&15 (query)
    const int wq = blockIdx.x >> 5, seg = blockIdx.x & 31;

    s16x8 qh[4], ql[4];
#pragma unroll
    for (int s = 0; s < 4; ++s) {
        int st = wq * 4 + s;
        qh[s] = *(const s16x8*)(QFh + (st * 64 + l) * 8);
        ql[s] = *(const s16x8*)(QFl + (st * 64 + l) * 8);
    }
    float m1v[4] = {1e30f, 1e30f, 1e30f, 1e30f};
    float m2v[4] = {1e30f, 1e30f, 1e30f, 1e30f};
    int   m1i[4] = {0, 0, 0, 0};

#pragma unroll 2
    for (int t = 0; t < 16; ++t) {
        int tile = seg * 16 + t;
        s16x8 ah = *(const s16x8*)(EFh + (tile * 64 + l) * 8);
        s16x8 al = *(const s16x8*)(EFl + (tile * 64 + l) * 8);
        f32x4 en = *(const f32x4*)(enorm + tile * 16 + lq);
        int bc = tile * 16 + lq;
#pragma unroll
        for (int s = 0; s < 4; ++s) {
            f32x4 acc = __builtin_amdgcn_mfma_f32_16x16x32_bf16(ah, qh[s], en, 0, 0, 0);
            acc = __builtin_amdgcn_mfma_f32_16x16x32_bf16(ah, ql[s], acc, 0, 0, 0);
            acc = __builtin_amdgcn_mfma_f32_16x16x32_bf16(al, qh[s], acc, 0, 0, 0);
#pragma unroll
            for (int r = 0; r < 4; ++r) {   // codes ascend: strict < keeps first idx
                float v = acc[r];
                bool lt = v < m1v[s];
                float m2c = fminf(m2v[s], v);
                m2v[s] = lt ? m1v[s] : m2c;
                m1i[s] = lt ? (bc + r) : m1i[s];
                m1v[s] = fminf(m1v[s], v);
            }
        }
    }
    // merge lanes {l, l^16, l^32, l^48} (same query col), tournament-exact
#pragma unroll
    for (int s = 0; s < 4; ++s) {
        u64 key = ((u64)flip_bits(__float_as_uint(m1v[s])) << 32) | (u32)m1i[s];
        float m2 = m2v[s];
#pragma unroll
        for (int off = 16; off <= 32; off <<= 1) {
            u64 ko = __shfl_xor(key, off, 64);
            float m2o = __shfl_xor(m2, off, 64);
            u64 kmax = ko > key ? ko : key;
            m2 = fminf(fminf(m2, m2o), unflip_val((u32)(kmax >> 32)));
            key = ko < key ? ko : key;
        }
        if (l < 16) {
            int q = wq * 64 + s * 16 + l;
            PARTK[seg * NQ + q] = key;
            PARTM2[seg * NQ + q] = m2;
        }
    }
}

// ---------------- K3: finalize + block-local exact rescan (k_final+k_exact merged) ----
// 64 blocks x 256: each thread merges 32 segs for one query (k_final body
// verbatim). Uncertain queries collected in LDS (expected ~0-3/block at
// MARGIN=0.01); the block then rescans each cooperatively with the k_exact
// inner loop. All coordination is intra-block (LDS + __syncthreads) — no
// cross-block sync, no fences, no ulist/uct global round-trip.
__global__ __launch_bounds__(256) void k_finalx(
    const u64* __restrict__ PARTK, const float* __restrict__ PARTM2,
    const float* __restrict__ f, const float* __restrict__ emb,
    const float* __restrict__ enorm,
    int* __restrict__ out_idx, int* __restrict__ counts) {
    __shared__ int ulist_s[256];
    __shared__ int ucnt_s;
    __shared__ u64 wred[4];
    const int tid = threadIdx.x;
    if (tid == 0) ucnt_s = 0;
    __syncthreads();

    // ---- phase 1: merge 32 segments, certainty test (verbatim k_final) ----
    int q = blockIdx.x * 256 + tid;
    u64 K = PARTK[q]; float M2 = PARTM2[q];
#pragma unroll
    for (int s = 1; s < NSEG; ++s) {
        u64 k = PARTK[s * NQ + q]; float m2 = PARTM2[s * NQ + q];
        u64 kmax = k > K ? k : K;
        M2 = fminf(fminf(M2, m2), unflip_val((u32)(kmax >> 32)));
        K = k < K ? k : K;
    }
    int idx = (int)(K & 0xffffffffull);
    out_idx[q] = idx;
    float m1 = unflip_val((u32)(K >> 32));
    if (M2 - m1 > MARGIN) {                   // NaN-safe: NaN -> uncertain
        atomicAdd(&counts[idx], 1);
    } else {
        int p = atomicAdd(&ucnt_s, 1);        // block-local list (<=256)
        ulist_s[p] = q;
    }
    __syncthreads();

    // ---- phase 2: cooperative exact fp32 rescan of this block's uncertain ----
    const int uc = ucnt_s;
    for (int i = 0; i < uc; ++i) {
        int qu = ulist_s[i];
        const float* fq = f + (qu >> 13) * BSTR + (qu & (PLANE - 1));
        float qv[CDIM];
#pragma unroll
        for (int c = 0; c < CDIM; ++c) qv[c] = -2.0f * fq[c * PLANE];
        u64 k0 = ~0ull;
        for (int jj = 0; jj < 32; ++jj) {
            int j = tid + 256 * jj;
            const float4* er = (const float4*)(emb + j * CDIM);
            float d0 = enorm[j];
#pragma unroll
            for (int c4 = 0; c4 < 8; ++c4) {
                float4 v = er[c4];
                d0 = fmaf(qv[c4 * 4 + 0], v.x, d0); d0 = fmaf(qv[c4 * 4 + 1], v.y, d0);
                d0 = fmaf(qv[c4 * 4 + 2], v.z, d0); d0 = fmaf(qv[c4 * 4 + 3], v.w, d0);
            }
            u64 nk = ((u64)flip_bits(__float_as_uint(d0)) << 32) | (u32)j;
            if (nk < k0) k0 = nk;
        }
#pragma unroll
        for (int off = 1; off <= 32; off <<= 1) {
            u64 o0 = __shfl_xor(k0, off, 64); if (o0 < k0) k0 = o0;
        }
        if ((tid & 63) == 0) wred[tid >> 6] = k0;
        __syncthreads();
        if (tid == 0) {
            u64 b0 = wred[0];
#pragma unroll
            for (int w = 1; w < 4; ++w) if (wred[w] < b0) b0 = wred[w];
            int i0 = (int)(b0 & 0xffffffffull);
            out_idx[qu] = i0;
            atomicAdd(&counts[i0], 1);
        }
        __syncthreads();
    }
}

// ---------------- K4: FH2 rows + guard zero + FUSED vocab_usage (block 81) ------------
__global__ void k_fh2(const int* __restrict__ idx, const float* __restrict__ emb,
                      u16* __restrict__ FH2h, u16* __restrict__ FH2l,
                      const int* __restrict__ counts, float* __restrict__ out) {
    __shared__ int us[4];
    int t = blockIdx.x * 256 + threadIdx.x;   // 82*256 = 20992
    if (t < NQ) {
        int id = idx[t];
        const float4* e = (const float4*)(emb + id * CDIM);
        s16x8 vh[4], vl[4];
#pragma unroll
        for (int r = 0; r < 8; ++r) {
            float4 v = e[r];
            float vv[4] = {v.x, v.y, v.z, v.w};
#pragma unroll
            for (int j = 0; j < 4; ++j) {
                int q = r * 4 + j;
                u16 hb = bf16_rne(vv[j]);
                float hf = __uint_as_float(((u32)hb) << 16);
                vh[q >> 3][q & 7] = (short)hb;
                vl[q >> 3][q & 7] = (short)bf16_rne(vv[j] - hf);
            }
        }
        u16* dh_ = FH2h + t * CDIM;
        u16* dl_ = FH2l + t * CDIM;
#pragma unroll
        for (int r = 0; r < 4; ++r) {
            *(s16x8*)(dh_ + r * 8) = vh[r];
            *(s16x8*)(dl_ + r * 8) = vl[r];
        }
    } else if (t < 20736) {
        // zero guards: 4 regions (FH2h lo/hi, FH2l lo/hi), each GUARD*32 u16
        int g = t - NQ;                       // 0..4351
        int r = g / 1088, off = (g % 1088) * 16;
        u32* dst;
        if (r == 0)      dst = (u32*)(FH2h - GUARD * CDIM);
        else if (r == 1) dst = (u32*)(FH2h + NQ * CDIM);
        else if (r == 2) dst = (u32*)(FH2l - GUARD * CDIM);
        else             dst = (u32*)(FH2l + NQ * CDIM);
#pragma unroll
        for (int i = 0; i < 16; ++i) dst[off + i] = 0;
    } else {
        // block 81: vocab_usage (counts final after k_finalx, stream-ordered)
        int tid = threadIdx.x;
        int used = 0;
#pragma unroll
        for (int r = 0; r < 32; ++r) used += (counts[tid + 256 * r] > 0) ? 1 : 0;
#pragma unroll
        for (int off = 32; off > 0; off >>= 1) used += __shfl_down(used, off, 64);
        if ((tid & 63) == 0) us[tid >> 6] = used;
        __syncthreads();
        if (tid == 0) {
            int u = us[0] + us[1] + us[2] + us[3];
            out[NEL + 1] = ((float)u / (float)VSZ) * 100.0f;
        }
    }
}

// ---------------- K5: conv — 3-way TAP-SPLIT MFMA (R9) + loss direct to out[NEL] ------
__global__ __launch_bounds__(192) void k_convm2(
    const u16* __restrict__ FH2h, const u16* __restrict__ FH2l,
    const u16* __restrict__ WFh, const u16* __restrict__ WFl,
    const int* __restrict__ idx, const float* __restrict__ emb,
    const float* __restrict__ bias, const float* __restrict__ f,
    float* __restrict__ out) {
    __shared__ float part[3][64][4];          // 3 KB
    const int l = threadIdx.x & 63;
    const int wv = threadIdx.x >> 6;          // 0..2 -> dt = wv-1
    const int ntile = blockIdx.x >> 1, cot = blockIdx.x & 1;
    const int co = cot * 16 + (l & 15);
    const int k0 = (l >> 4) * 8;

    const int nA = ntile * 16 + (l & 15);     // A row this lane loads
    const int pA = nA & (PLANE - 1);
    const int tA = pA >> 10, hA = (pA >> 5) & 31, wA = pA & 31;
    const u16* pAh = FH2h + nA * CDIM + k0;
    const u16* pAl = FH2l + nA * CDIM + k0;

    const int ddt = wv - 1;
    const bool okt = ((unsigned)(tA + ddt) < 8u);

    f32x4 a0 = {0.f, 0.f, 0.f, 0.f}, a1 = a0, a2 = a0;
    const s16x8 zf = {0, 0, 0, 0, 0, 0, 0, 0};
#pragma unroll
    for (int v = 0; v < 9; ++v) {
        const int dh = v / 3 - 1, dw = v % 3 - 1;
        const int u = wv * 9 + v;             // same tap<->WF pairing as R7/R9
        const int du = ddt * 1024 + dh * 32 + dw;
        bool ok = okt && ((unsigned)(hA + dh) < 32u) && ((unsigned)(wA + dw) < 32u);
        s16x8 ah = *(const s16x8*)(pAh + du * CDIM);
        s16x8 al = *(const s16x8*)(pAl + du * CDIM);
        if (!ok) { ah = zf; al = zf; }        // guard reads discarded exactly
        int nt = 2 * u + cot;
        s16x8 bh = *(const s16x8*)(WFh + (nt * 64 + l) * 8);
        s16x8 bl = *(const s16x8*)(WFl + (nt * 64 + l) * 8);
        a0 = __builtin_amdgcn_mfma_f32_16x16x32_bf16(ah, bh, a0, 0, 0, 0);
        a1 = __builtin_amdgcn_mfma_f32_16x16x32_bf16(ah, bl, a1, 0, 0, 0);
        a2 = __builtin_amdgcn_mfma_f32_16x16x32_bf16(al, bh, a2, 0, 0, 0);
    }
#pragma unroll
    for (int r = 0; r < 4; ++r) part[wv][l][r] = a0[r] + a1[r] + a2[r];
    __syncthreads();
    if (wv != 0) return;

    f32x4 acc;
#pragma unroll
    for (int r = 0; r < 4; ++r)
        acc[r] = part[0][l][r] + part[1][l][r] + part[2][l][r];
    const float bv = bias[co];

    // epilogue: rows n0..n0+3 (consecutive within plane), col co
    const int n0 = ntile * 16 + (l >> 4) * 4;
    const int b = n0 >> 13, p0 = n0 & (PLANE - 1);
    const long fb = (long)b * BSTR + (long)co * PLANE + p0;
    const float4 f4 = *(const float4*)(f + fb);
    const int4 iv = *(const int4*)(idx + n0);
    float o0 = 0.5f * emb[iv.x * CDIM + co] + 0.5f * (acc[0] + bv);
    float o1 = 0.5f * emb[iv.y * CDIM + co] + 0.5f * (acc[1] + bv);
    float o2 = 0.5f * emb[iv.z * CDIM + co] + 0.5f * (acc[2] + bv);
    float o3 = 0.5f * emb[iv.w * CDIM + co] + 0.5f * (acc[3] + bv);
    float4 o4 = {o0, o1, o2, o3};
    *(float4*)(out + fb) = o4;
    float d0 = o0 - f4.x, d1 = o1 - f4.y, d2 = o2 - f4.z, d3 = o3 - f4.w;
    float s = fmaf(d0, d0, fmaf(d1, d1, fmaf(d2, d2, d3 * d3)));
#pragma unroll
    for (int off = 32; off > 0; off >>= 1) s += __shfl_down(s, off, 64);
    if (l == 0) atomicAdd(out + NEL, s * (1.25f / (float)NEL));   // vq_loss in place
}

extern "C" void kernel_launch(void* const* d_in, const int* in_sizes, int n_in,
                              void* d_out, int out_size, void* d_ws, size_t ws_size,
                              hipStream_t stream) {
    const float* f      = (const float*)d_in[0];
    const float* emb    = (const float*)d_in[1];
    const float* conv_w = (const float*)d_in[2];
    const float* conv_b = (const float*)d_in[3];
    float* out = (float*)d_out;
    float* ws = (float*)d_ws;

    // workspace layout (float offsets), total 2,422,528 floats (~9.69 MB,
    // under the 9.75 MB proven in R2)
    float* enorm    = ws;                          // 8192
    int*   counts   = (int*)(ws + 8192);           // 8192
    int*   idxb     = (int*)(ws + 16384);          // 16384 (ulist/uct now unused)
    u16*   EFh      = (u16*)(ws + 49408);          // 131072 f -> 180480
    u16*   EFl      = (u16*)(ws + 180480);         // 131072 f -> 311552
    u16*   QFh      = (u16*)(ws + 311552);         // 262144 f -> 573696
    u16*   QFl      = (u16*)(ws + 573696);         // 262144 f -> 835840
    u16*   WFh      = (u16*)(ws + 835840);         // 6912 f   -> 842752
    u16*   WFl      = (u16*)(ws + 842752);         // 6912 f   -> 849664
    u64*   PARTK    = (u64*)(ws + 849664);         // 32x16384 u64 -> 1898240
    float* PARTM2   = ws + 1898240;                // 524288 f -> 2422528
    // FH2 aliases PARTK (dead after k_finalx). Each array:
    // (16384 + 2*GUARD) rows x 32 u16 = 593920 u16 = 296960 f.
    u16*   FH2h     = (u16*)(ws + 849664)  + GUARD * CDIM;   // ends f-off 1146624
    u16*   FH2l     = (u16*)(ws + 1146624) + GUARD * CDIM;   // ends f-off 1443584

    k_prep   <<<430, 256, 0, stream>>>(f, emb, conv_w, EFh, EFl, QFh, QFl,
                                       WFh, WFl, enorm, counts);
    k_mfma3  <<<8192, 64, 0, stream>>>(QFh, QFl, EFh, EFl, enorm, PARTK, PARTM2);
    k_finalx <<<64, 256, 0, stream>>>(PARTK, PARTM2, f, emb, enorm, idxb, counts);
    k_fh2    <<<82, 256, 0, stream>>>(idxb, emb, FH2h, FH2l, counts, out);
    k_convm2 <<<2048, 192, 0, stream>>>(FH2h, FH2l, WFh, WFl, idxb, emb,
                                        conv_b, f, out);
}

// Round 15
// 182.078 us; speedup vs baseline: 1.7621x; 1.7621x over previous
//
#include <hip/hip_runtime.h>

// Problem constants (B=2, C=32, T=8, H=32, W=32, V=8192)
#define NQ    16384      // B*T*H*W
#define CDIM  32
#define VSZ   8192
#define PLANE 8192       // T*H*W
#define BSTR  262144     // C*PLANE
#define NEL   524288     // B*C*T*H*W
#define MARGIN 0.010f    // certainty margin (covers bf16x3 error ~1e-3 with 10x slack)
#define NSEG  32         // V-segments for argmin
#define GUARD 1088       // FH2 row guard (> max |tap shift| = 1057)

typedef unsigned long long u64;
typedef unsigned int u32;
typedef unsigned short u16;
using f32x4 = __attribute__((ext_vector_type(4))) float;
using s16x8 = __attribute__((ext_vector_type(8))) short;

__device__ __forceinline__ u32 flip_bits(u32 b) {
    return (b & 0x80000000u) ? ~b : (b | 0x80000000u);
}
__device__ __forceinline__ float unflip_val(u32 b) {
    u32 u = (b & 0x80000000u) ? (b ^ 0x80000000u) : ~b;
    return __uint_as_float(u);
}
__device__ __forceinline__ u16 bf16_rne(float x) {
    u32 u = __float_as_uint(x);
    return (u16)((u + 0x7fffu + ((u >> 16) & 1u)) >> 16);
}

// ---------------- K1: prep — bf16 hi/lo frags (EF/QF/WF) + enorm + zeros ----------------
// Frag layout (proven R1/R2): lane l holds A/B[row|col = l&15][k = (l>>4)*8 + i].
// WF packs Wmat[col = u*32+co][k = ci] = cw[co*864 + ci*27 + u], 54 col-tiles.
__global__ void k_prep(const float* __restrict__ f, const float* __restrict__ emb,
                       const float* __restrict__ cw,
                       u16* __restrict__ EFh, u16* __restrict__ EFl,
                       u16* __restrict__ QFh, u16* __restrict__ QFl,
                       u16* __restrict__ WFh, u16* __restrict__ WFl,
                       float* __restrict__ enorm, int* __restrict__ counts,
                       int* __restrict__ uct) {
    int t = blockIdx.x * 256 + threadIdx.x;   // 430*256 = 110080, used 109952
    if (t < 32768) {                          // EF: 512 code tiles x 64 lanes
        int tile = t >> 6, l = t & 63;
        int row = tile * 16 + (l & 15);
        int k0 = (l >> 4) * 8;
        const float* src = emb + row * CDIM + k0;
        s16x8 vh, vl;
#pragma unroll
        for (int i = 0; i < 8; ++i) {
            float v = src[i];
            u16 hb = bf16_rne(v);
            float hf = __uint_as_float(((u32)hb) << 16);
            vh[i] = (short)hb;
            vl[i] = (short)bf16_rne(v - hf);
        }
        *(s16x8*)(EFh + t * 8) = vh;
        *(s16x8*)(EFl + t * 8) = vl;
    } else if (t < 98304) {                   // QF: 1024 query subtiles, q' = -2q
        int t2 = t - 32768;
        int st = t2 >> 6, l = t2 & 63;
        int n = st * 16 + (l & 15);
        int k0 = (l >> 4) * 8;
        int b = n >> 13, p = n & (PLANE - 1);
        const float* fq = f + b * BSTR + p;
        s16x8 vh, vl;
#pragma unroll
        for (int i = 0; i < 8; ++i) {
            float v = -2.0f * fq[(k0 + i) * PLANE];
            u16 hb = bf16_rne(v);
            float hf = __uint_as_float(((u32)hb) << 16);
            vh[i] = (short)hb;
            vl[i] = (short)bf16_rne(v - hf);
        }
        *(s16x8*)(QFh + t2 * 8) = vh;
        *(s16x8*)(QFl + t2 * 8) = vl;
    } else if (t < 106496) {                  // enorm + zero counts + init scalars
        int j = t - 98304;
        const float4* row = (const float4*)(emb + j * CDIM);
        float s = 0.f;
#pragma unroll
        for (int r = 0; r < 8; ++r) {
            float4 v = row[r];
            s += v.x * v.x + v.y * v.y + v.z * v.z + v.w * v.w;
        }
        enorm[j] = s;
        counts[j] = 0;
        if (j == 0) { *uct = 0; }
    } else if (t < 109952) {                  // WF: 54 col-tiles x 64 lanes
        int i = t - 106496;
        int nt = i >> 6, l = i & 63;
        int col = nt * 16 + (l & 15);         // < 864
        int co = col & 31, u = col >> 5;
        int k0 = (l >> 4) * 8;
        s16x8 vh, vl;
#pragma unroll
        for (int j = 0; j < 8; ++j) {
            int ci = k0 + j;
            float v = cw[co * 864 + ci * 27 + u];
            u16 hb = bf16_rne(v);
            float hf = __uint_as_float(((u32)hb) << 16);
            vh[j] = (short)hb;
            vl[j] = (short)bf16_rne(v - hf);
        }
        *(s16x8*)(WFh + i * 8) = vh;
        *(s16x8*)(WFl + i * 8) = vl;
    }
}

// ---------------- K2: single-pass exact MFMA argmin (QT=4, 1-wave blocks, 32 segs) ----
// grid 8192 x 64. EMPIRICAL OPTIMUM at ~44.6us across seven variants
// (R1/R2/R4/R6/R7/R12/R13): issue-bound (VALUBusy 66% + MfmaUtil 22%) on the
// 5-op exact (m1,m2,idx) tracking. No cross-block fences (R10: 6x slowdown).
__global__ __launch_bounds__(64) void k_mfma3(
    const u16* __restrict__ QFh, const u16* __restrict__ QFl,
    const u16* __restrict__ EFh, const u16* __restrict__ EFl,
    const float* __restrict__ enorm,
    u64* __restrict__ PARTK, float* __restrict__ PARTM2) {
    const int l = threadIdx.x;
    const int lq = (l >> 4) * 4;   // D rows lq..lq+3 (codes), col = l&15 (query)
    const int wq = blockIdx.x >> 5, seg = blockIdx.x & 31;

    s16x8 qh[4], ql[4];
#pragma unroll
    for (int s = 0; s < 4; ++s) {
        int st = wq * 4 + s;
        qh[s] = *(const s16x8*)(QFh + (st * 64 + l) * 8);
        ql[s] = *(const s16x8*)(QFl + (st * 64 + l) * 8);
    }
    float m1v[4] = {1e30f, 1e30f, 1e30f, 1e30f};
    float m2v[4] = {1e30f, 1e30f, 1e30f, 1e30f};
    int   m1i[4] = {0, 0, 0, 0};

#pragma unroll 2
    for (int t = 0; t < 16; ++t) {
        int tile = seg * 16 + t;
        s16x8 ah = *(const s16x8*)(EFh + (tile * 64 + l) * 8);
        s16x8 al = *(const s16x8*)(EFl + (tile * 64 + l) * 8);
        f32x4 en = *(const f32x4*)(enorm + tile * 16 + lq);
        int bc = tile * 16 + lq;
#pragma unroll
        for (int s = 0; s < 4; ++s) {
            f32x4 acc = __builtin_amdgcn_mfma_f32_16x16x32_bf16(ah, qh[s], en, 0, 0, 0);
            acc = __builtin_amdgcn_mfma_f32_16x16x32_bf16(ah, ql[s], acc, 0, 0, 0);
            acc = __builtin_amdgcn_mfma_f32_16x16x32_bf16(al, qh[s], acc, 0, 0, 0);
#pragma unroll
            for (int r = 0; r < 4; ++r) {   // codes ascend: strict < keeps first idx
                float v = acc[r];
                bool lt = v < m1v[s];
                float m2c = fminf(m2v[s], v);
                m2v[s] = lt ? m1v[s] : m2c;
                m1i[s] = lt ? (bc + r) : m1i[s];
                m1v[s] = fminf(m1v[s], v);
            }
        }
    }
    // merge lanes {l, l^16, l^32, l^48} (same query col), tournament-exact
#pragma unroll
    for (int s = 0; s < 4; ++s) {
        u64 key = ((u64)flip_bits(__float_as_uint(m1v[s])) << 32) | (u32)m1i[s];
        float m2 = m2v[s];
#pragma unroll
        for (int off = 16; off <= 32; off <<= 1) {
            u64 ko = __shfl_xor(key, off, 64);
            float m2o = __shfl_xor(m2, off, 64);
            u64 kmax = ko > key ? ko : key;
            m2 = fminf(fminf(m2, m2o), unflip_val((u32)(kmax >> 32)));
            key = ko < key ? ko : key;
        }
        if (l < 16) {
            int q = wq * 64 + s * 16 + l;
            PARTK[seg * NQ + q] = key;
            PARTM2[seg * NQ + q] = m2;
        }
    }
}

// ---------------- K3: finalize — merge 32 segments, certainty test (R9) ----------------
__global__ void k_final(const u64* __restrict__ PARTK, const float* __restrict__ PARTM2,
                        int* __restrict__ out_idx, int* __restrict__ counts,
                        int* __restrict__ uct, int* __restrict__ ulist) {
    int q = blockIdx.x * 256 + threadIdx.x;   // 16384
    u64 K = PARTK[q]; float M2 = PARTM2[q];
#pragma unroll
    for (int s = 1; s < NSEG; ++s) {
        u64 k = PARTK[s * NQ + q]; float m2 = PARTM2[s * NQ + q];
        u64 kmax = k > K ? k : K;
        M2 = fminf(fminf(M2, m2), unflip_val((u32)(kmax >> 32)));
        K = k < K ? k : K;
    }
    int idx = (int)(K & 0xffffffffull);
    out_idx[q] = idx;
    float m1 = unflip_val((u32)(K >> 32));
    if (M2 - m1 > MARGIN) {                   // NaN-safe: NaN -> uncertain
        atomicAdd(&counts[idx], 1);
    } else {
        int p = atomicAdd(uct, 1);            // bounded by NQ
        ulist[p] = q;
    }
}

// ---------------- K4: exact fp32 rescan for uncertain queries (R9) ----------------
// 128 blocks x 2 queries/pass: distributes the O(10^3) uncertain queries with
// deep ILP (R14 lesson: block-local rescan over 64 blocks serializes -> 180us).
__global__ __launch_bounds__(256) void k_exact(
    const int* __restrict__ ulist, const int* __restrict__ uct,
    const float* __restrict__ f, const float* __restrict__ emb,
    const float* __restrict__ enorm, int* __restrict__ out_idx,
    int* __restrict__ counts) {
    __shared__ u64 wred[4][2];
    const int tid = threadIdx.x;
    const int uc = *uct;
    for (int base = blockIdx.x * 2; base < uc; base += 256) {
        int nq = uc - base; if (nq > 2) nq = 2;
        int q0 = ulist[base];
        int q1 = (nq > 1) ? ulist[base + 1] : q0;
        float qv0[CDIM], qv1[CDIM];
        {
            const float* f0 = f + (q0 >> 13) * BSTR + (q0 & (PLANE - 1));
            const float* f1 = f + (q1 >> 13) * BSTR + (q1 & (PLANE - 1));
#pragma unroll
            for (int c = 0; c < CDIM; ++c) {
                qv0[c] = -2.0f * f0[c * PLANE];
                qv1[c] = -2.0f * f1[c * PLANE];
            }
        }
        u64 k0 = ~0ull, k1 = ~0ull;
        for (int jj = 0; jj < 32; ++jj) {
            int j = tid + 256 * jj;
            const float4* er = (const float4*)(emb + j * CDIM);
            float d0 = enorm[j], d1 = d0;
#pragma unroll
            for (int c4 = 0; c4 < 8; ++c4) {
                float4 v = er[c4];
                d0 = fmaf(qv0[c4 * 4 + 0], v.x, d0); d0 = fmaf(qv0[c4 * 4 + 1], v.y, d0);
                d0 = fmaf(qv0[c4 * 4 + 2], v.z, d0); d0 = fmaf(qv0[c4 * 4 + 3], v.w, d0);
                d1 = fmaf(qv1[c4 * 4 + 0], v.x, d1); d1 = fmaf(qv1[c4 * 4 + 1], v.y, d1);
                d1 = fmaf(qv1[c4 * 4 + 2], v.z, d1); d1 = fmaf(qv1[c4 * 4 + 3], v.w, d1);
            }
            u64 nk0 = ((u64)flip_bits(__float_as_uint(d0)) << 32) | (u32)j;
            u64 nk1 = ((u64)flip_bits(__float_as_uint(d1)) << 32) | (u32)j;
            if (nk0 < k0) k0 = nk0;
            if (nk1 < k1) k1 = nk1;
        }
#pragma unroll
        for (int off = 1; off <= 32; off <<= 1) {
            u64 o0 = __shfl_xor(k0, off, 64); if (o0 < k0) k0 = o0;
            u64 o1 = __shfl_xor(k1, off, 64); if (o1 < k1) k1 = o1;
        }
        if ((tid & 63) == 0) { wred[tid >> 6][0] = k0; wred[tid >> 6][1] = k1; }
        __syncthreads();
        if (tid == 0) {
            u64 b0 = wred[0][0], b1 = wred[0][1];
#pragma unroll
            for (int w = 1; w < 4; ++w) {
                if (wred[w][0] < b0) b0 = wred[w][0];
                if (wred[w][1] < b1) b1 = wred[w][1];
            }
            int i0 = (int)(b0 & 0xffffffffull);
            out_idx[q0] = i0; atomicAdd(&counts[i0], 1);
            if (nq > 1) {
                int i1 = (int)(b1 & 0xffffffffull);
                out_idx[q1] = i1; atomicAdd(&counts[i1], 1);
            }
        }
        __syncthreads();
    }
}

// ---------------- K5: FH2 rows + guard zero + FUSED vocab_usage (block 81) ------------
__global__ void k_fh2(const int* __restrict__ idx, const float* __restrict__ emb,
                      u16* __restrict__ FH2h, u16* __restrict__ FH2l,
                      const int* __restrict__ counts, float* __restrict__ out) {
    __shared__ int us[4];
    int t = blockIdx.x * 256 + threadIdx.x;   // 82*256 = 20992
    if (t < NQ) {
        int id = idx[t];
        const float4* e = (const float4*)(emb + id * CDIM);
        s16x8 vh[4], vl[4];
#pragma unroll
        for (int r = 0; r < 8; ++r) {
            float4 v = e[r];
            float vv[4] = {v.x, v.y, v.z, v.w};
#pragma unroll
            for (int j = 0; j < 4; ++j) {
                int q = r * 4 + j;
                u16 hb = bf16_rne(vv[j]);
                float hf = __uint_as_float(((u32)hb) << 16);
                vh[q >> 3][q & 7] = (short)hb;
                vl[q >> 3][q & 7] = (short)bf16_rne(vv[j] - hf);
            }
        }
        u16* dh_ = FH2h + t * CDIM;
        u16* dl_ = FH2l + t * CDIM;
#pragma unroll
        for (int r = 0; r < 4; ++r) {
            *(s16x8*)(dh_ + r * 8) = vh[r];
            *(s16x8*)(dl_ + r * 8) = vl[r];
        }
    } else if (t < 20736) {
        // zero guards: 4 regions (FH2h lo/hi, FH2l lo/hi), each GUARD*32 u16
        int g = t - NQ;                       // 0..4351
        int r = g / 1088, off = (g % 1088) * 16;
        u32* dst;
        if (r == 0)      dst = (u32*)(FH2h - GUARD * CDIM);
        else if (r == 1) dst = (u32*)(FH2h + NQ * CDIM);
        else if (r == 2) dst = (u32*)(FH2l - GUARD * CDIM);
        else             dst = (u32*)(FH2l + NQ * CDIM);
#pragma unroll
        for (int i = 0; i < 16; ++i) dst[off + i] = 0;
    } else {
        // block 81: vocab_usage (counts final after k_exact, stream-ordered)
        int tid = threadIdx.x;
        int used = 0;
#pragma unroll
        for (int r = 0; r < 32; ++r) used += (counts[tid + 256 * r] > 0) ? 1 : 0;
#pragma unroll
        for (int off = 32; off > 0; off >>= 1) used += __shfl_down(used, off, 64);
        if ((tid & 63) == 0) us[tid >> 6] = used;
        __syncthreads();
        if (tid == 0) {
            int u = us[0] + us[1] + us[2] + us[3];
            out[NEL + 1] = ((float)u / (float)VSZ) * 100.0f;
        }
    }
}

// ---------------- K6: conv — 3-way TAP-SPLIT MFMA (R9) + loss direct to out[NEL] ------
__global__ __launch_bounds__(192) void k_convm2(
    const u16* __restrict__ FH2h, const u16* __restrict__ FH2l,
    const u16* __restrict__ WFh, const u16* __restrict__ WFl,
    const int* __restrict__ idx, const float* __restrict__ emb,
    const float* __restrict__ bias, const float* __restrict__ f,
    float* __restrict__ out) {
    __shared__ float part[3][64][4];          // 3 KB
    const int l = threadIdx.x & 63;
    const int wv = threadIdx.x >> 6;          // 0..2 -> dt = wv-1
    const int ntile = blockIdx.x >> 1, cot = blockIdx.x & 1;
    const int co = cot * 16 + (l & 15);
    const int k0 = (l >> 4) * 8;

    const int nA = ntile * 16 + (l & 15);     // A row this lane loads
    const int pA = nA & (PLANE - 1);
    const int tA = pA >> 10, hA = (pA >> 5) & 31, wA = pA & 31;
    const u16* pAh = FH2h + nA * CDIM + k0;
    const u16* pAl = FH2l + nA * CDIM + k0;

    const int ddt = wv - 1;
    const bool okt = ((unsigned)(tA + ddt) < 8u);

    f32x4 a0 = {0.f, 0.f, 0.f, 0.f}, a1 = a0, a2 = a0;
    const s16x8 zf = {0, 0, 0, 0, 0, 0, 0, 0};
#pragma unroll
    for (int v = 0; v < 9; ++v) {
        const int dh = v / 3 - 1, dw = v % 3 - 1;
        const int u = wv * 9 + v;             // same tap<->WF pairing as R7/R9
        const int du = ddt * 1024 + dh * 32 + dw;
        bool ok = okt && ((unsigned)(hA + dh) < 32u) && ((unsigned)(wA + dw) < 32u);
        s16x8 ah = *(const s16x8*)(pAh + du * CDIM);
        s16x8 al = *(const s16x8*)(pAl + du * CDIM);
        if (!ok) { ah = zf; al = zf; }        // guard reads discarded exactly
        int nt = 2 * u + cot;
        s16x8 bh = *(const s16x8*)(WFh + (nt * 64 + l) * 8);
        s16x8 bl = *(const s16x8*)(WFl + (nt * 64 + l) * 8);
        a0 = __builtin_amdgcn_mfma_f32_16x16x32_bf16(ah, bh, a0, 0, 0, 0);
        a1 = __builtin_amdgcn_mfma_f32_16x16x32_bf16(ah, bl, a1, 0, 0, 0);
        a2 = __builtin_amdgcn_mfma_f32_16x16x32_bf16(al, bh, a2, 0, 0, 0);
    }
#pragma unroll
    for (int r = 0; r < 4; ++r) part[wv][l][r] = a0[r] + a1[r] + a2[r];
    __syncthreads();
    if (wv != 0) return;

    f32x4 acc;
#pragma unroll
    for (int r = 0; r < 4; ++r)
        acc[r] = part[0][l][r] + part[1][l][r] + part[2][l][r];
    const float bv = bias[co];

    // epilogue: rows n0..n0+3 (consecutive within plane), col co
    const int n0 = ntile * 16 + (l >> 4) * 4;
    const int b = n0 >> 13, p0 = n0 & (PLANE - 1);
    const long fb = (long)b * BSTR + (long)co * PLANE + p0;
    const float4 f4 = *(const float4*)(f + fb);
    const int4 iv = *(const int4*)(idx + n0);
    float o0 = 0.5f * emb[iv.x * CDIM + co] + 0.5f * (acc[0] + bv);
    float o1 = 0.5f * emb[iv.y * CDIM + co] + 0.5f * (acc[1] + bv);
    float o2 = 0.5f * emb[iv.z * CDIM + co] + 0.5f * (acc[2] + bv);
    float o3 = 0.5f * emb[iv.w * CDIM + co] + 0.5f * (acc[3] + bv);
    float4 o4 = {o0, o1, o2, o3};
    *(float4*)(out + fb) = o4;
    float d0 = o0 - f4.x, d1 = o1 - f4.y, d2 = o2 - f4.z, d3 = o3 - f4.w;
    float s = fmaf(d0, d0, fmaf(d1, d1, fmaf(d2, d2, d3 * d3)));
#pragma unroll
    for (int off = 32; off > 0; off >>= 1) s += __shfl_down(s, off, 64);
    if (l == 0) atomicAdd(out + NEL, s * (1.25f / (float)NEL));   // vq_loss in place
}

extern "C" void kernel_launch(void* const* d_in, const int* in_sizes, int n_in,
                              void* d_out, int out_size, void* d_ws, size_t ws_size,
                              hipStream_t stream) {
    const float* f      = (const float*)d_in[0];
    const float* emb    = (const float*)d_in[1];
    const float* conv_w = (const float*)d_in[2];
    const float* conv_b = (const float*)d_in[3];
    float* out = (float*)d_out;
    float* ws = (float*)d_ws;

    // workspace layout (float offsets), total 2,422,528 floats (~9.69 MB,
    // under the 9.75 MB proven in R2)
    float* enorm    = ws;                          // 8192
    int*   counts   = (int*)(ws + 8192);           // 8192
    int*   idxb     = (int*)(ws + 16384);          // 16384
    int*   uct      = (int*)(ws + 32769);          // 1 (+pad to 32772)
    int*   ulist    = (int*)(ws + 32772);          // 16384 -> 49156, pad 49408
    u16*   EFh      = (u16*)(ws + 49408);          // 131072 f -> 180480
    u16*   EFl      = (u16*)(ws + 180480);         // 131072 f -> 311552
    u16*   QFh      = (u16*)(ws + 311552);         // 262144 f -> 573696
    u16*   QFl      = (u16*)(ws + 573696);         // 262144 f -> 835840
    u16*   WFh      = (u16*)(ws + 835840);         // 6912 f   -> 842752
    u16*   WFl      = (u16*)(ws + 842752);         // 6912 f   -> 849664
    u64*   PARTK    = (u64*)(ws + 849664);         // 32x16384 u64 -> 1898240
    float* PARTM2   = ws + 1898240;                // 524288 f -> 2422528
    // FH2 aliases PARTK (dead after k_final; k_exact doesn't touch it).
    // Each array: (16384 + 2*GUARD) rows x 32 u16 = 593920 u16 = 296960 f.
    u16*   FH2h     = (u16*)(ws + 849664)  + GUARD * CDIM;   // ends f-off 1146624
    u16*   FH2l     = (u16*)(ws + 1146624) + GUARD * CDIM;   // ends f-off 1443584

    k_prep   <<<430, 256, 0, stream>>>(f, emb, conv_w, EFh, EFl, QFh, QFl,
                                       WFh, WFl, enorm, counts, uct);
    k_mfma3  <<<8192, 64, 0, stream>>>(QFh, QFl, EFh, EFl, enorm, PARTK, PARTM2);
    k_final  <<<64, 256, 0, stream>>>(PARTK, PARTM2, idxb, counts, uct, ulist);
    k_exact  <<<128, 256, 0, stream>>>(ulist, uct, f, emb, enorm, idxb, counts);
    k_fh2    <<<82, 256, 0, stream>>>(idxb, emb, FH2h, FH2l, counts, out);
    k_convm2 <<<2048, 192, 0, stream>>>(FH2h, FH2l, WFh, WFl, idxb, emb,
                                        conv_b, f, out);
}